// Round 5
// baseline (305.262 us; speedup 1.0000x reference)
//
#include <hip/hip_runtime.h>
#include <string.h>

typedef __bf16 bf16;
typedef __bf16 bf16x4 __attribute__((ext_vector_type(4)));
typedef __bf16 bf16x8 __attribute__((ext_vector_type(8)));
typedef float f32x4 __attribute__((ext_vector_type(4)));

#define BN_EPS 1e-5f
#define NORM_EPS 1e-12f

// ---- prep: Ct[k][d] = clusters[d][k] * bn_scale[k]; zero asum ----
__global__ __launch_bounds__(256) void k_prep(const float* __restrict__ clusters,
                                              const float* __restrict__ bnw,
                                              const float* __restrict__ bnv,
                                              bf16* __restrict__ Ct,
                                              float* __restrict__ asum) {
  int idx = blockIdx.x * 256 + threadIdx.x;   // 0..32767 (= 64*512)
  if (idx < 64 * 64) asum[idx] = 0.f;
  int k = idx >> 9, d = idx & 511;
  float scale = bnw[k] / sqrtf(bnv[k] + BN_EPS);
  Ct[idx] = (bf16)(clusters[d * 80 + k] * scale);
}

// ---- fused: one pass over x. Round-5 change: 512 blocks = (b, n-eighth),
//   2 blocks/CU (LDS 73.3 KB) so staging of one block overlaps compute of the
//   other — the serial stage->barrier->MFMA chain was the round-4 bottleneck.
//   Enabled by reading logits B-frags DIRECTLY from global Ct (64 KB, L2-hot;
//   bit-identical values) instead of staging Cl into LDS.
//   All index math (X2 subtiled+swizzled layout, softmax, Tl, V-GEMM gather)
//   is byte-identical to the round-4 verified kernel. ----
__global__ __launch_bounds__(256, 2) void k_fused(const float* __restrict__ x,
                                                  const bf16* __restrict__ Ct,
                                                  float* __restrict__ Vp,
                                                  float* __restrict__ asum_g) {
  __shared__ __align__(16) bf16 X2[32768];      // 64 KB  x-chunk, subtiled+swizzled
  __shared__ __align__(16) bf16 Tl[64 * 72];    // 9 KB   a-tile [k][n] pitch 72
  __shared__ float asum_l[64];
  const int t = threadIdx.x;
  const int w = t >> 6;          // wave 0..3
  const int l = t & 63;
  const int q = l >> 4;          // quad 0..3
  const int m16 = l & 15;
  const int b = blockIdx.x >> 3;       // batch
  const int q8 = blockIdx.x & 7;       // n-eighth
  const int nbase = q8 << 7;           // n offset within batch (128 n per block)

  if (t < 64) asum_l[t] = 0.f;

  f32x4 vacc[8][4];
#pragma unroll
  for (int i = 0; i < 8; ++i)
#pragma unroll
    for (int j = 0; j < 4; ++j) vacc[i][j] = (f32x4){0.f, 0.f, 0.f, 0.f};

  const int angL = w * 4 + (m16 >> 2);          // logits-row ng
  const int anrL = (m16 & 3) ^ (angL & 3);      // swizzled nr

  for (int ch = 0; ch < 2; ++ch) {
    const int n0 = nbase + ch * 64;
    // ---- stage X chunk: 64 n x 512 d fp32 -> bf16, subtiled+swizzled (verified) ----
#pragma unroll 8
    for (int p = 0; p < 32; ++p) {
      int id = p * 256 + t;            // 0..8191
      int nn = id >> 7, c = id & 127;  // c = 4-float chunk of d
      float4 v = *(const float4*)(x + (size_t)(b * 1024 + n0 + nn) * 512 + c * 4);
      int dc = c >> 2, dl0 = (c & 3) * 4;
      int ng = nn >> 2, nrp = (nn & 3) ^ (ng & 3);
      bf16x4 pk;
      pk[0] = (bf16)v.x; pk[1] = (bf16)v.y; pk[2] = (bf16)v.z; pk[3] = (bf16)v.w;
      *(bf16x4*)(&X2[dc * 1024 + ng * 64 + nrp * 16 + dl0]) = pk;
    }
    __syncthreads();   // X2 staged

    // ---- logits GEMM: lacc[nt] over K=512; B-frags straight from L2-hot Ct ----
    f32x4 lacc[4];
#pragma unroll
    for (int j = 0; j < 4; ++j) lacc[j] = (f32x4){0.f, 0.f, 0.f, 0.f};
#pragma unroll
    for (int dt8 = 0; dt8 < 8; ++dt8) {
#pragma unroll
      for (int ks = 0; ks < 2; ++ks) {
        int dc = dt8 * 4 + ks * 2 + (q >> 1);
        bf16x8 afrag = *(const bf16x8*)(&X2[dc * 1024 + angL * 64 + anrL * 16 + (q & 1) * 8]);
#pragma unroll
        for (int nt = 0; nt < 4; ++nt) {
          bf16x8 bfrag = *(const bf16x8*)(Ct + (size_t)(nt * 16 + m16) * 512
                                             + dt8 * 64 + ks * 32 + q * 8);
          lacc[nt] = __builtin_amdgcn_mfma_f32_16x16x32_bf16(afrag, bfrag, lacc[nt], 0, 0, 0);
        }
      }
    }

    // ---- softmax over 64 k (verified). C/D: row n = w*16+q*4+r, col k = nt*16+m16 ----
    float csum[4] = {0.f, 0.f, 0.f, 0.f};
#pragma unroll
    for (int r = 0; r < 4; ++r) {
      float v[4];
#pragma unroll
      for (int nt = 0; nt < 4; ++nt) v[nt] = lacc[nt][r];
      float mx = fmaxf(fmaxf(v[0], v[1]), fmaxf(v[2], v[3]));
#pragma unroll
      for (int off = 1; off < 16; off <<= 1) mx = fmaxf(mx, __shfl_xor(mx, off));
      float e[4];
      float s = 0.f;
#pragma unroll
      for (int nt = 0; nt < 4; ++nt) { e[nt] = __expf(v[nt] - mx); s += e[nt]; }
#pragma unroll
      for (int off = 1; off < 16; off <<= 1) s += __shfl_xor(s, off);
      float inv = 1.f / s;
      int nrow = w * 16 + q * 4 + r;   // local n (0..63)
#pragma unroll
      for (int nt = 0; nt < 4; ++nt) {
        bf16 ab = (bf16)(e[nt] * inv);
        Tl[(nt * 16 + m16) * 72 + nrow] = ab;
        csum[nt] += (float)ab;
      }
    }
#pragma unroll
    for (int nt = 0; nt < 4; ++nt) {
      float cs = csum[nt];
      cs += __shfl_xor(cs, 16);
      cs += __shfl_xor(cs, 32);
      if (q == 0) atomicAdd(&asum_l[nt * 16 + m16], cs);
    }
    __syncthreads();   // Tl ready for all waves

    // ---- V-GEMM: vacc[dt][nt] += Xt[d][n] * a[n][k]; wave w owns d in [w*128, w*128+128) ----
#pragma unroll
    for (int ks = 0; ks < 2; ++ks) {
      bf16x8 bfr[4];
#pragma unroll
      for (int nt = 0; nt < 4; ++nt)
        bfr[nt] = *(const bf16x8*)(&Tl[(nt * 16 + m16) * 72 + ks * 32 + q * 8]);
#pragma unroll
      for (int dt = 0; dt < 8; ++dt) {
        int dc = w * 8 + dt;
        bf16x8 af;
#pragma unroll
        for (int j = 0; j < 8; ++j) {
          int ng = ks * 8 + q * 2 + (j >> 2);
          int nrp = (j & 3) ^ (ng & 3);
          af[j] = X2[dc * 1024 + ng * 64 + nrp * 16 + m16];
        }
#pragma unroll
        for (int nt = 0; nt < 4; ++nt)
          vacc[dt][nt] = __builtin_amdgcn_mfma_f32_16x16x32_bf16(af, bfr[nt], vacc[dt][nt], 0, 0, 0);
      }
    }
    __syncthreads();   // before next chunk overwrites X2/Tl
  }

  if (t < 64) atomicAdd(&asum_g[b * 64 + t], asum_l[t]);

  // write V partial: Vp[q8][b][d][k]. C/D: row d = (w*8+dt)*16 + q*4 + r, col k = nt*16+m16
  float* vp = Vp + (size_t)(q8 * 64 + b) * 512 * 64;
#pragma unroll
  for (int dt = 0; dt < 8; ++dt) {
#pragma unroll
    for (int nt = 0; nt < 4; ++nt) {
      int k = nt * 16 + m16;
#pragma unroll
      for (int r = 0; r < 4; ++r) {
        int d = (w * 8 + dt) * 16 + q * 4 + r;
        vp[(size_t)d * 64 + k] = vacc[dt][nt][r];
      }
    }
  }
}

// ---- combine: out = sum of 8 partials - a_sum*c2; write unscaled out + ssq partials.
//      f32x4-vectorized (1 KB per wave-instr). ----
__global__ __launch_bounds__(256) void k_combine(const float* __restrict__ Vp,
                                                 const float* __restrict__ asum_g,
                                                 const float* __restrict__ c2,
                                                 float* __restrict__ ssq_p,
                                                 float* __restrict__ out) {
  __shared__ float ssl[16][68];
  const int t = threadIdx.x;
  const int b = blockIdx.x >> 3;
  const int d0 = (blockIdx.x & 7) << 6;
  const int kq = (t & 15) * 4;     // k-float4 base
  const int dg = t >> 4;           // d-subgroup 0..15
  const size_t J = (size_t)64 * 512 * 64;       // partial stride
  const float* vpb = Vp + (size_t)b * 512 * 64;
  f32x4 sA = *(const f32x4*)(asum_g + b * 64 + kq);
  f32x4 sq = (f32x4){0.f, 0.f, 0.f, 0.f};
#pragma unroll
  for (int p = 0; p < 4; ++p) {
    int d = d0 + p * 16 + dg;
    size_t od = (size_t)d * 64 + kq;
    f32x4 v = *(const f32x4*)(vpb + od);
#pragma unroll
    for (int j = 1; j < 8; ++j) v += *(const f32x4*)(vpb + j * J + od);
    f32x4 c2v = *(const f32x4*)(c2 + d * 64 + kq);
    v = v - sA * c2v;
    *(f32x4*)(out + ((size_t)b * 512 + d) * 64 + kq) = v;
    sq += v * v;
  }
  *(f32x4*)(&ssl[dg][kq]) = sq;
  __syncthreads();
  if (t < 64) {
    float s = 0.f;
#pragma unroll
    for (int g = 0; g < 16; ++g) s += ssl[g][t];
    ssq_p[(size_t)blockIdx.x * 64 + t] = s;
  }
}

// ---- scale: per-(b,k) intra-norm + per-b global norm, in-place on out (verified) ----
__global__ __launch_bounds__(256) void k_scale(const float* __restrict__ ssq_p,
                                               float* __restrict__ out) {
  __shared__ float sc[64];
  const int t = threadIdx.x;
  const int b = blockIdx.x >> 3;
  const int d0 = (blockIdx.x & 7) << 6;
  if (t < 64) {
    float tot = 0.f;
#pragma unroll
    for (int j = 0; j < 8; ++j) tot += ssq_p[(size_t)(b * 8 + j) * 64 + t];
    float rinv = 1.f / fmaxf(sqrtf(tot), NORM_EPS);
    float g = tot * rinv * rinv;     // ||v_k||^2 after intra-norm
#pragma unroll
    for (int off = 1; off < 64; off <<= 1) g += __shfl_xor(g, off);
    float ginv = 1.f / fmaxf(sqrtf(g), NORM_EPS);
    sc[t] = rinv * ginv;
  }
  __syncthreads();
  const int k = t & 63, dr = t >> 6;
  float s = sc[k];
  float* ob = out + ((size_t)b * 512 + d0) * 64;
#pragma unroll
  for (int d = dr; d < 64; d += 4) {
    int i = d * 64 + k;
    ob[i] = ob[i] * s;
  }
}

extern "C" void kernel_launch(void* const* d_in, const int* in_sizes, int n_in,
                              void* d_out, int out_size, void* d_ws, size_t ws_size,
                              hipStream_t stream) {
  const float* x        = (const float*)d_in[0];
  const float* clusters = (const float*)d_in[1];
  const float* bnw      = (const float*)d_in[2];
  // d_in[3] = bn_bias, d_in[4] = bn_mean: computed-but-never-applied in the reference.
  const float* bnv      = (const float*)d_in[5];
  const float* c2       = (const float*)d_in[6];
  float* out = (float*)d_out;
  char* ws = (char*)d_ws;
  float* asum  = (float*)(ws);                         // 64*64*4        = 16384 B
  float* ssq_p = (float*)(ws + 32768);                 // 512*64*4       = 131072 B
  bf16*  Ct    = (bf16*)(ws + 32768 + 131072);         // 64*512*2       = 65536 B
  float* Vp    = (float*)(ws + 229376);                // 8*64*512*64*4  = 67108864 B

  k_prep<<<128, 256, 0, stream>>>(clusters, bnw, bnv, Ct, asum);
  k_fused<<<512, 256, 0, stream>>>(x, Ct, Vp, asum);
  k_combine<<<512, 256, 0, stream>>>(Vp, asum, c2, ssq_p, out);
  k_scale<<<512, 256, 0, stream>>>(ssq_p, out);
}

// Round 7
// 228.258 us; speedup vs baseline: 1.3374x; 1.3374x over previous
//
#include <hip/hip_runtime.h>
#include <string.h>

typedef __bf16 bf16;
typedef __bf16 bf16x4 __attribute__((ext_vector_type(4)));
typedef __bf16 bf16x8 __attribute__((ext_vector_type(8)));
typedef float f32x4 __attribute__((ext_vector_type(4)));

#define BN_EPS 1e-5f
#define NORM_EPS 1e-12f

// LDS-only barrier: orders ds ops across the workgroup WITHOUT draining vmcnt,
// so prefetched global loads stay in flight (T4/T14). sched_barrier(0) pins
// code motion around the inline asm (rule 18).
#define LBAR() do { \
  asm volatile("s_waitcnt lgkmcnt(0)" ::: "memory"); \
  __builtin_amdgcn_sched_barrier(0); \
  __builtin_amdgcn_s_barrier(); \
  __builtin_amdgcn_sched_barrier(0); \
} while (0)

// ---- prep: Ct[k][d] = clusters[d][k] * bn_scale[k]; zero asum ----
__global__ __launch_bounds__(256) void k_prep(const float* __restrict__ clusters,
                                              const float* __restrict__ bnw,
                                              const float* __restrict__ bnv,
                                              bf16* __restrict__ Ct,
                                              float* __restrict__ asum) {
  int idx = blockIdx.x * 256 + threadIdx.x;   // 0..32767 (= 64*512)
  if (idx < 64 * 64) asum[idx] = 0.f;
  int k = idx >> 9, d = idx & 511;
  float scale = bnw[k] / sqrtf(bnv[k] + BN_EPS);
  Ct[idx] = (bf16)(clusters[d * 80 + k] * scale);
}

// ---- fused: round-4 verified structure (256 blocks = b x n-quarter, 1 block/CU,
//   Cl resident in LDS) + two changes:
//   1) T14 async-stage: chunk ch+1's 32 float4 loads issued into REGISTERS before
//      computing ch; cvt+ds_write after the post-compute __syncthreads (the only
//      vmcnt drain). Intra-compute barriers are LDS-only (LBAR) so the prefetch
//      stays in flight. Registers are the double buffer — LDS stays 145 KB.
//   2) X2 swizzle s = (n&3)^((n>>2)&3)^((n>>3)&3)^(dc&3) on write+both reads:
//      staging writes, V-gather u16, logits afrag all reach bank-conflict floor.
//   X2 layout: elem index = dc*1024 + (n>>2)*64 + s*16 + (d&15), dc = d>>4. ----
__global__ __launch_bounds__(256, 1) void k_fused(const float* __restrict__ x,
                                                  const bf16* __restrict__ Ct,
                                                  float* __restrict__ Vp,
                                                  float* __restrict__ asum_g) {
  __shared__ __align__(16) bf16 X2[32768];      // 64 KB  x-chunk (64 n x 512 d)
  __shared__ __align__(16) bf16 Cl[8][64 * 72]; // 72 KB  Ct tiles (verified)
  __shared__ __align__(16) bf16 Tl[64 * 72];    // 9 KB   a-tile [k][n] pitch 72
  __shared__ float asum_l[64];
  const int t = threadIdx.x;
  const int w = t >> 6;          // wave 0..3
  const int l = t & 63;
  const int q = l >> 4;          // quad 0..3
  const int m16 = l & 15;
  const int b = blockIdx.x >> 2;       // batch
  const int q4 = blockIdx.x & 3;       // n-quarter
  const int nbase = q4 << 8;           // 256 n per block

  // Cl resident: 8 tiles of [64 k][64 d] pitch 72 (round-4 verified)
#pragma unroll
  for (int p = 0; p < 16; ++p) {
    int id = p * 256 + t;
    int tile = id >> 9, r = (id >> 3) & 63, c = id & 7;
    *(uint4*)(&Cl[tile][r * 72 + c * 8]) = *(const uint4*)(Ct + r * 512 + tile * 64 + c * 8);
  }
  if (t < 64) asum_l[t] = 0.f;

  f32x4 vacc[8][4];
#pragma unroll
  for (int i = 0; i < 8; ++i)
#pragma unroll
    for (int j = 0; j < 4; ++j) vacc[i][j] = (f32x4){0.f, 0.f, 0.f, 0.f};

  // staging lane constants: thread covers (nn = 2p+tb, c = cc) — round-4 mapping
  const int tb = t >> 7;
  const int cc = t & 127;
  const int dcw = cc >> 2, dl0 = (cc & 3) * 4, swp = dcw & 3;
  const float* xb = x + (((size_t)(b * 1024 + tb)) << 9) + cc * 4;

  // logits afrag lane bases (ks=0 / ks=1): dc = dt8*4 + ks*2 + (q>>1)
  const int sbase = (m16 & 3) ^ ((m16 >> 2) & 3) ^ ((w * 2 + (m16 >> 3)) & 3);
  const int ngl64 = (w * 4 + (m16 >> 2)) * 64;
  const int A0 = (q >> 1) * 1024 + ngl64 + ((sbase ^ (q >> 1)) & 3) * 16 + (q & 1) * 8;
  const int A1 = 2048 + (q >> 1) * 1024 + ngl64 + ((sbase ^ (2 + (q >> 1))) & 3) * 16 + (q & 1) * 8;

  // V-gather lane table: af elem = vbase + dt*1024 + ks*512 + (gv[j] ^ ((dt&3)<<4))
  int gv[8];
#pragma unroll
  for (int j = 0; j < 8; ++j) {
    int fj = ((j & 3) ^ ((2 * q + (j >> 2)) & 3) ^ q) & 3;
    gv[j] = q * 128 + (j >> 2) * 64 + (fj << 4) + m16;
  }
  const int vbase = w * 8192;

  float4 v[32];
  // ---- prologue: load + write chunk 0 ----
#pragma unroll
  for (int p = 0; p < 32; ++p)
    v[p] = *(const float4*)(xb + (size_t)nbase * 512 + p * 1024);
#pragma unroll
  for (int p = 0; p < 32; ++p) {
    int nn = 2 * p + tb;
    int sv = (nn & 3) ^ ((nn >> 2) & 3) ^ ((nn >> 3) & 3) ^ swp;
    bf16x4 pk;
    pk[0] = (bf16)v[p].x; pk[1] = (bf16)v[p].y; pk[2] = (bf16)v[p].z; pk[3] = (bf16)v[p].w;
    *(bf16x4*)(&X2[dcw * 1024 + (nn >> 2) * 64 + sv * 16 + dl0]) = pk;
  }
  LBAR();

  for (int ch = 0; ch < 4; ++ch) {
    // ---- T14: issue next chunk's global loads now; consumed after __syncthreads ----
    if (ch < 3) {
      const float* xc = xb + (size_t)(nbase + (ch + 1) * 64) * 512;
#pragma unroll
      for (int p = 0; p < 32; ++p) v[p] = *(const float4*)(xc + p * 1024);
    }

    // ---- logits GEMM over K=512 (round-4 structure, swizzled A reads) ----
    f32x4 lacc[4];
#pragma unroll
    for (int j = 0; j < 4; ++j) lacc[j] = (f32x4){0.f, 0.f, 0.f, 0.f};
#pragma unroll
    for (int dt8 = 0; dt8 < 8; ++dt8) {
      bf16x8 a0 = *(const bf16x8*)(&X2[A0 + dt8 * 4096]);
      bf16x8 a1 = *(const bf16x8*)(&X2[A1 + dt8 * 4096]);
#pragma unroll
      for (int nt = 0; nt < 4; ++nt) {
        bf16x8 b0 = *(const bf16x8*)(&Cl[dt8][(nt * 16 + m16) * 72 + q * 8]);
        lacc[nt] = __builtin_amdgcn_mfma_f32_16x16x32_bf16(a0, b0, lacc[nt], 0, 0, 0);
      }
#pragma unroll
      for (int nt = 0; nt < 4; ++nt) {
        bf16x8 b1 = *(const bf16x8*)(&Cl[dt8][(nt * 16 + m16) * 72 + 32 + q * 8]);
        lacc[nt] = __builtin_amdgcn_mfma_f32_16x16x32_bf16(a1, b1, lacc[nt], 0, 0, 0);
      }
    }

    // ---- softmax over 64 k (round-4 verbatim). C/D: row n = w*16+q*4+r, col = nt*16+m16 ----
    float csum[4] = {0.f, 0.f, 0.f, 0.f};
#pragma unroll
    for (int r = 0; r < 4; ++r) {
      float vv[4];
#pragma unroll
      for (int nt = 0; nt < 4; ++nt) vv[nt] = lacc[nt][r];
      float mx = fmaxf(fmaxf(vv[0], vv[1]), fmaxf(vv[2], vv[3]));
#pragma unroll
      for (int off = 1; off < 16; off <<= 1) mx = fmaxf(mx, __shfl_xor(mx, off));
      float e[4];
      float s = 0.f;
#pragma unroll
      for (int nt = 0; nt < 4; ++nt) { e[nt] = __expf(vv[nt] - mx); s += e[nt]; }
#pragma unroll
      for (int off = 1; off < 16; off <<= 1) s += __shfl_xor(s, off);
      float inv = 1.f / s;
      int nrow = w * 16 + q * 4 + r;
#pragma unroll
      for (int nt = 0; nt < 4; ++nt) {
        bf16 ab = (bf16)(e[nt] * inv);
        Tl[(nt * 16 + m16) * 72 + nrow] = ab;
        csum[nt] += (float)ab;
      }
    }
#pragma unroll
    for (int nt = 0; nt < 4; ++nt) {
      float cs = csum[nt];
      cs += __shfl_xor(cs, 16);
      cs += __shfl_xor(cs, 32);
      if (q == 0) atomicAdd(&asum_l[nt * 16 + m16], cs);
    }
    LBAR();   // Tl ready (LDS-only: prefetch loads stay in flight)

    // ---- V-GEMM (swizzled conflict-free u16 gather) ----
#pragma unroll
    for (int ks = 0; ks < 2; ++ks) {
      bf16x8 bfr[4];
#pragma unroll
      for (int nt = 0; nt < 4; ++nt)
        bfr[nt] = *(const bf16x8*)(&Tl[(nt * 16 + m16) * 72 + ks * 32 + q * 8]);
#pragma unroll
      for (int dt = 0; dt < 8; ++dt) {
        bf16x8 af;
#pragma unroll
        for (int j = 0; j < 8; ++j)
          af[j] = X2[vbase + dt * 1024 + ks * 512 + (gv[j] ^ ((dt & 3) << 4))];
#pragma unroll
        for (int nt = 0; nt < 4; ++nt)
          vacc[dt][nt] = __builtin_amdgcn_mfma_f32_16x16x32_bf16(af, bfr[nt], vacc[dt][nt], 0, 0, 0);
      }
    }
    __syncthreads();   // full drain: all waves done with X2/Tl; v[] loads complete

    // ---- write next chunk into X2 (cvt is the only staging VALU on the critical path) ----
    if (ch < 3) {
#pragma unroll
      for (int p = 0; p < 32; ++p) {
        int nn = 2 * p + tb;
        int sv = (nn & 3) ^ ((nn >> 2) & 3) ^ ((nn >> 3) & 3) ^ swp;
        bf16x4 pk;
        pk[0] = (bf16)v[p].x; pk[1] = (bf16)v[p].y; pk[2] = (bf16)v[p].z; pk[3] = (bf16)v[p].w;
        *(bf16x4*)(&X2[dcw * 1024 + (nn >> 2) * 64 + sv * 16 + dl0]) = pk;
      }
      LBAR();
    }
  }

  if (t < 64) atomicAdd(&asum_g[b * 64 + t], asum_l[t]);

  // write V partial: Vp[q4][b][d][k] (round-4 verbatim)
  float* vp = Vp + (size_t)(q4 * 64 + b) * 512 * 64;
#pragma unroll
  for (int dt = 0; dt < 8; ++dt) {
#pragma unroll
    for (int nt = 0; nt < 4; ++nt) {
      int k = nt * 16 + m16;
#pragma unroll
      for (int r = 0; r < 4; ++r) {
        int d = (w * 8 + dt) * 16 + q * 4 + r;
        vp[(size_t)d * 64 + k] = vacc[dt][nt][r];
      }
    }
  }
}

// ---- combine: out = sum of 4 partials - a_sum*c2; unscaled out + ssq partials ----
__global__ __launch_bounds__(256) void k_combine(const float* __restrict__ Vp,
                                                 const float* __restrict__ asum_g,
                                                 const float* __restrict__ c2,
                                                 float* __restrict__ ssq_p,
                                                 float* __restrict__ out) {
  __shared__ float ssl[16][68];
  const int t = threadIdx.x;
  const int b = blockIdx.x >> 3;
  const int d0 = (blockIdx.x & 7) << 6;
  const int kq = (t & 15) * 4;     // k-float4 base
  const int dg = t >> 4;           // d-subgroup 0..15
  const size_t J = (size_t)64 * 512 * 64;       // partial stride
  const float* vpb = Vp + (size_t)b * 512 * 64;
  f32x4 sA = *(const f32x4*)(asum_g + b * 64 + kq);
  f32x4 sq = (f32x4){0.f, 0.f, 0.f, 0.f};
#pragma unroll
  for (int p = 0; p < 4; ++p) {
    int d = d0 + p * 16 + dg;
    size_t od = (size_t)d * 64 + kq;
    f32x4 v = *(const f32x4*)(vpb + od);
#pragma unroll
    for (int j = 1; j < 4; ++j) v += *(const f32x4*)(vpb + j * J + od);
    f32x4 c2v = *(const f32x4*)(c2 + d * 64 + kq);
    v = v - sA * c2v;
    *(f32x4*)(out + ((size_t)b * 512 + d) * 64 + kq) = v;
    sq += v * v;
  }
  *(f32x4*)(&ssl[dg][kq]) = sq;
  __syncthreads();
  if (t < 64) {
    float s = 0.f;
#pragma unroll
    for (int g = 0; g < 16; ++g) s += ssl[g][t];
    ssq_p[(size_t)blockIdx.x * 64 + t] = s;
  }
}

// ---- scale: per-(b,k) intra-norm + per-b global norm, in-place (verified) ----
__global__ __launch_bounds__(256) void k_scale(const float* __restrict__ ssq_p,
                                               float* __restrict__ out) {
  __shared__ float sc[64];
  const int t = threadIdx.x;
  const int b = blockIdx.x >> 3;
  const int d0 = (blockIdx.x & 7) << 6;
  if (t < 64) {
    float tot = 0.f;
#pragma unroll
    for (int j = 0; j < 8; ++j) tot += ssq_p[(size_t)(b * 8 + j) * 64 + t];
    float rinv = 1.f / fmaxf(sqrtf(tot), NORM_EPS);
    float g = tot * rinv * rinv;     // ||v_k||^2 after intra-norm
#pragma unroll
    for (int off = 1; off < 64; off <<= 1) g += __shfl_xor(g, off);
    float ginv = 1.f / fmaxf(sqrtf(g), NORM_EPS);
    sc[t] = rinv * ginv;
  }
  __syncthreads();
  const int k = t & 63, dr = t >> 6;
  float s = sc[k];
  float* ob = out + ((size_t)b * 512 + d0) * 64;
#pragma unroll
  for (int d = dr; d < 64; d += 4) {
    int i = d * 64 + k;
    ob[i] = ob[i] * s;
  }
}

extern "C" void kernel_launch(void* const* d_in, const int* in_sizes, int n_in,
                              void* d_out, int out_size, void* d_ws, size_t ws_size,
                              hipStream_t stream) {
  const float* x        = (const float*)d_in[0];
  const float* clusters = (const float*)d_in[1];
  const float* bnw      = (const float*)d_in[2];
  // d_in[3] = bn_bias, d_in[4] = bn_mean: computed-but-never-applied in the reference.
  const float* bnv      = (const float*)d_in[5];
  const float* c2       = (const float*)d_in[6];
  float* out = (float*)d_out;
  char* ws = (char*)d_ws;
  float* asum  = (float*)(ws);                         // 64*64*4        = 16384 B
  float* ssq_p = (float*)(ws + 32768);                 // 512*64*4       = 131072 B
  bf16*  Ct    = (bf16*)(ws + 32768 + 131072);         // 64*512*2       = 65536 B
  float* Vp    = (float*)(ws + 229376);                // 4*64*512*64*4  = 33554432 B

  k_prep<<<128, 256, 0, stream>>>(clusters, bnw, bnv, Ct, asum);
  k_fused<<<256, 256, 0, stream>>>(x, Ct, Vp, asum);
  k_combine<<<512, 256, 0, stream>>>(Vp, asum, c2, ssq_p, out);
  k_scale<<<512, 256, 0, stream>>>(ssq_p, out);
}